// Round 3
// baseline (126.689 us; speedup 1.0000x reference)
//
#include <hip/hip_runtime.h>

// RoPE: out[..., 2i]   = cos*x[...,2i] - sin*x[...,2i+1]
//       out[..., 2i+1] = sin*x[...,2i] + cos*x[...,2i+1]
// x: (4,32,4096,128) fp32, sin/cos: (8192,64) fp32, pos: (B*H*S) int32.
// Memory-bound: ~518 MB compulsory traffic -> ~82 us floor at 6.3 TB/s.
// This version: 8 floats/thread/iter, nontemporal x/out (streamed once) so
// the 4 MB sin/cos tables stay hot in L2. Native clang vector type for the
// nontemporal builtins (HIP_vector_type is a struct and is rejected).

typedef float f32x4 __attribute__((ext_vector_type(4)));

__global__ __launch_bounds__(256)
void rope_kernel(const float* __restrict__ x,
                 const float* __restrict__ sinT,
                 const float* __restrict__ cosT,
                 const int* __restrict__ pos,
                 float* __restrict__ out,
                 int n8) {
    int idx = blockIdx.x * blockDim.x + threadIdx.x;
    int stride = gridDim.x * blockDim.x;
    for (int g = idx; g < n8; g += stride) {
        int row = g >> 4;                 // 128 floats/row = 16 chunks of 8
        int i0 = (g & 15) << 2;           // pair index within row: 0,4,...,60
        int p = pos[row];                 // shared by 16 consecutive lanes (cache bcast)
        const f32x4 s = *reinterpret_cast<const f32x4*>(sinT + p * 64 + i0);
        const f32x4 c = *reinterpret_cast<const f32x4*>(cosT + p * 64 + i0);
        const f32x4* xp = reinterpret_cast<const f32x4*>(x + 8ll * g);
        f32x4 v0 = __builtin_nontemporal_load(xp);
        f32x4 v1 = __builtin_nontemporal_load(xp + 1);
        f32x4 r0, r1;
        r0.x = c.x * v0.x - s.x * v0.y;
        r0.y = s.x * v0.x + c.x * v0.y;
        r0.z = c.y * v0.z - s.y * v0.w;
        r0.w = s.y * v0.z + c.y * v0.w;
        r1.x = c.z * v1.x - s.z * v1.y;
        r1.y = s.z * v1.x + c.z * v1.y;
        r1.z = c.w * v1.z - s.w * v1.w;
        r1.w = s.w * v1.z + c.w * v1.w;
        f32x4* op = reinterpret_cast<f32x4*>(out + 8ll * g);
        __builtin_nontemporal_store(r0, op);
        __builtin_nontemporal_store(r1, op + 1);
    }
}

extern "C" void kernel_launch(void* const* d_in, const int* in_sizes, int n_in,
                              void* d_out, int out_size, void* d_ws, size_t ws_size,
                              hipStream_t stream) {
    const float* x    = (const float*)d_in[0];
    const float* sinT = (const float*)d_in[1];
    const float* cosT = (const float*)d_in[2];
    const int*   pos  = (const int*)d_in[3];
    float* out = (float*)d_out;

    int n8 = out_size / 8;                // 8,388,608 chunks of 8 floats
    const int block = 256;
    int grid = 2048;                      // 256 CU x 8 blocks/CU, grid-stride rest
    rope_kernel<<<grid, block, 0, stream>>>(x, sinT, cosT, pos, out, n8);
}

// Round 4
// 108.829 us; speedup vs baseline: 1.1641x; 1.1641x over previous
//
#include <hip/hip_runtime.h>

// RoPE: out[..., 2i]   = cos*x[...,2i] - sin*x[...,2i+1]
//       out[..., 2i+1] = sin*x[...,2i] + cos*x[...,2i+1]
// x: (4,32,4096,128) fp32, pos: (B*H*S) int32 (harness converts int64).
// sin/cos tables are NOT loaded: each row re-reads 512 B of table, and the
// streaming x/out evicts the 4 MB tables from L2, costing ~250 MB of extra
// HBM fetch. Instead compute sin/cos on the fly: per-thread inv_freq/(2pi)
// is loop-invariant (hoisted exp2f), per-iter cost is 2 fract + 2 v_sin +
// 2 v_cos (~4% of transcendental throughput). v_sin_f32 takes REVOLUTIONS
// (cdna4_isa.md), so 1/2pi is folded into the hoisted constant.
// Compulsory traffic: 256 MB read + 256 MB write + 2 MB pos -> ~82 us floor.

typedef float f32x4 __attribute__((ext_vector_type(4)));

__global__ __launch_bounds__(256)
void rope_kernel(const float* __restrict__ x,
                 const int* __restrict__ pos,
                 float* __restrict__ out,
                 int n4) {
    int idx = blockIdx.x * blockDim.x + threadIdx.x;
    int stride = gridDim.x * blockDim.x;   // 524288, multiple of 32 -> (g&31) loop-invariant
    const float K = 0.20762051f;           // log2(10000)/64
    const float INV2PI = 0.15915494309189535f;
    int i0 = (idx & 31) << 1;              // frequency index of first pair (0,2,..,62)
    float ifr0 = exp2f(-(float)i0 * K) * INV2PI;        // inv_freq[i0]   / 2pi
    float ifr1 = exp2f(-(float)(i0 + 1) * K) * INV2PI;  // inv_freq[i0+1] / 2pi
    for (int g = idx; g < n4; g += stride) {
        int row = g >> 5;                  // 128 floats/row = 32 float4 groups
        int p = pos[row];                  // broadcast across 32 lanes via cache
        float pf = (float)p;
        float a0 = __builtin_amdgcn_fractf(pf * ifr0);  // revolutions in [0,1)
        float a1 = __builtin_amdgcn_fractf(pf * ifr1);
        float s0 = __builtin_amdgcn_sinf(a0);
        float c0 = __builtin_amdgcn_cosf(a0);
        float s1 = __builtin_amdgcn_sinf(a1);
        float c1 = __builtin_amdgcn_cosf(a1);
        f32x4 v = *reinterpret_cast<const f32x4*>(x + 4ll * g);
        f32x4 r;
        r.x = c0 * v.x - s0 * v.y;
        r.y = s0 * v.x + c0 * v.y;
        r.z = c1 * v.z - s1 * v.w;
        r.w = s1 * v.z + c1 * v.w;
        *reinterpret_cast<f32x4*>(out + 4ll * g) = r;
    }
}

extern "C" void kernel_launch(void* const* d_in, const int* in_sizes, int n_in,
                              void* d_out, int out_size, void* d_ws, size_t ws_size,
                              hipStream_t stream) {
    const float* x   = (const float*)d_in[0];
    const int*   pos = (const int*)d_in[3];
    float* out = (float*)d_out;

    int n4 = out_size / 4;                 // 16,777,216 float4 groups
    const int block = 256;
    int grid = 2048;                       // 256 CU x 8 blocks/CU, grid-stride rest
    rope_kernel<<<grid, block, 0, stream>>>(x, pos, out, n4);
}